// Round 1
// 418.684 us; speedup vs baseline: 1.0763x; 1.0763x over previous
//
#include <hip/hip_runtime.h>
#include <hip/hip_bf16.h>

// Problem constants
#define Bsz 4
#define Tsz 2048
#define Dsz 1024
#define Ssz 16
#define Esz 2048
#define Mrows (Bsz*Tsz)        // 8192

typedef __attribute__((ext_vector_type(8))) short short8;
typedef __attribute__((ext_vector_type(4))) float floatx4;
typedef __attribute__((ext_vector_type(8))) int int8v;
typedef __attribute__((ext_vector_type(4))) int int4v;

__device__ __forceinline__ void async_ld16(const void* g, void* l) {
    __builtin_amdgcn_global_load_lds(
        (const __attribute__((address_space(1))) void*)g,
        (__attribute__((address_space(3))) void*)l,
        16, 0, 0);
}

__device__ __forceinline__ float sigmoidf_(float v) { return 1.f / (1.f + expf(-v)); }
__device__ __forceinline__ float bf2f(unsigned short u) {
    union { unsigned u32; float f; } c; c.u32 = (unsigned)u << 16; return c.f;
}
__device__ __forceinline__ int pk_fp8x4(float a, float b, float c, float d) {
    int lo = __builtin_amdgcn_cvt_pk_fp8_f32(a, b, 0, 0);
    int hi = __builtin_amdgcn_cvt_pk_fp8_f32(c, d, 0, 0);
    return (lo & 0xFFFF) | (hi << 16);
}

// s_waitcnt immediates (gfx9): vm[3:0]|exp[6:4]|lgkm[11:8]|vm[15:14]
#define WAIT_VM(N)   (0xF70 | (N))
#define WAIT_LGKM(N) (0xC07F | ((N) << 8))

// ---------------------------------------------------------------------------
// merged conversions: x -> fp8 (x1), in_w -> fp8 (x64), dt_w -> fp8 (x64),
// out_w -> fp8 (x64).  Scales lift 0.02-sd weights out of e4m3 subnormals;
// the matching unscale rides free in the MFMA scale operand.
// ---------------------------------------------------------------------------
#define CV_S0 2097152   // x:     8388608 f32 / 4
#define CV_S1 3145728   // in_w: +4194304 / 4
#define CV_S2 4194304   // dt_w: +4194304 / 4
#define CV_S3 4718592   // out_w:+2097152 / 4
__global__ void cvt_all(const float4* __restrict__ x,  const float4* __restrict__ iw,
                        const float4* __restrict__ dw, const float4* __restrict__ ow,
                        int* __restrict__ x8, int* __restrict__ iw8,
                        int* __restrict__ dw8, int* __restrict__ ow8) {
    int i = blockIdx.x * blockDim.x + threadIdx.x;
    const int stride = gridDim.x * blockDim.x;
    for (; i < CV_S3; i += stride) {
        if (i < CV_S0) {
            float4 v = x[i];
            x8[i] = pk_fp8x4(v.x, v.y, v.z, v.w);
        } else if (i < CV_S1) {
            const int j = i - CV_S0;
            float4 v = iw[j];
            iw8[j] = pk_fp8x4(v.x * 64.f, v.y * 64.f, v.z * 64.f, v.w * 64.f);
        } else if (i < CV_S2) {
            const int j = i - CV_S1;
            float4 v = dw[j];
            dw8[j] = pk_fp8x4(v.x * 64.f, v.y * 64.f, v.z * 64.f, v.w * 64.f);
        } else {
            const int j = i - CV_S2;
            float4 v = ow[j];
            ow8[j] = pk_fp8x4(v.x * 64.f, v.y * 64.f, v.z * 64.f, v.w * 64.f);
        }
    }
}

// ---------------------------------------------------------------------------
// MX-fp8 GEMM: C[M,N] = (A*2^(SA-127)) @ (Bw*2^(SB-127))^T (+bias).
// 128x128 block tile (R9: N-tile 64 -> 128; 13% MfmaUtil showed the
// double-barrier phase overhead dominating 8 MFMAs -> double density to
// 16 MFMA/phase/wave, per-wave 64x64, m148-style), BK=128B, 4 waves 2x2.
// 2-stage LDS (64KB, 2 blk/CU), dist-2 DMA prefetch, vmcnt(8) in-loop,
// mod-8 XOR chunk swizzle.
// MODE: 0 bf16 store, 1 softplus rowsum, 2 fp32 resid + ys[row]*acc.
// ---------------------------------------------------------------------------
template<int MODE, int SA, int SB>
__launch_bounds__(256, 2)
__global__ void gemm_f8(const unsigned char* __restrict__ A,
                        const unsigned char* __restrict__ Bw,
                        const float* __restrict__ bias,
                        int M, int N, int K,
                        __hip_bfloat16* __restrict__ outb,
                        float* __restrict__ rowsum,
                        const float* __restrict__ resid,
                        const float* __restrict__ ysv,
                        float* __restrict__ outf) {
    __shared__ __align__(16) unsigned char sA[2 * 16384];  // 128 rows x 128B
    __shared__ __align__(16) unsigned char sB[2 * 16384];  // 128 rows x 128B

    const int tid  = threadIdx.x;
    const int wave = tid >> 6, lane = tid & 63;
    const int wm = wave >> 1, wn = wave & 1;
    const int q = lane >> 4, lr = lane & 15;

    // XCD-aware remap (R6-proven): each XCD owns a contiguous M-stripe.
    const int gx = gridDim.x, gy = gridDim.y;
    const int flat = blockIdx.y * gx + blockIdx.x;
    const int stripe = gy >> 3;
    const int xcd = flat & 7, local = flat >> 3;
    const int mt = xcd * stripe + (local % stripe);
    const int nt = local / stripe;
    const int m0 = mt * 128, n0 = nt * 128;

    floatx4 acc[4][4];
#pragma unroll
    for (int i = 0; i < 4; ++i)
#pragma unroll
        for (int j = 0; j < 4; ++j) acc[i][j] = (floatx4){0.f, 0.f, 0.f, 0.f};

    // staging: A 16KB = 16 x 1KB (4 instr/wave), B 16KB (4 instr/wave);
    // LDS slot s of row r holds global chunk s^(r&7) (16B chunks).
    const unsigned char* pa[4];
    const unsigned char* pb[4];
#pragma unroll
    for (int i = 0; i < 4; ++i) {
        const int idx = i * 256 + tid, row = idx >> 3, s = idx & 7;
        pa[i] = A + (size_t)(m0 + row) * K + ((s ^ (row & 7)) * 16);
        pb[i] = Bw + (size_t)(n0 + row) * K + ((s ^ (row & 7)) * 16);
    }

    // fragment LDS byte offsets (A frag i at +i*2048, B frag j at +j*2048;
    // (r+16i)&7 == r&7 so swizzle field is frag-invariant)
    const int rA = wm * 64 + lr, rB = wn * 64 + lr;
    const int oA0 = rA * 128 + (((2 * q)     ^ (rA & 7)) * 16);
    const int oA1 = rA * 128 + (((2 * q + 1) ^ (rA & 7)) * 16);
    const int oB0 = rB * 128 + (((2 * q)     ^ (rB & 7)) * 16);
    const int oB1 = rB * 128 + (((2 * q + 1) ^ (rB & 7)) * 16);

#define F8_ISSUE(ST) do {                                                      \
        _Pragma("unroll")                                                      \
        for (int i = 0; i < 4; ++i) {                                          \
            async_ld16(pa[i], &sA[(ST) * 16384 + (i * 256 + wave * 64) * 16]); \
            pa[i] += 128;                                                      \
        }                                                                      \
        _Pragma("unroll")                                                      \
        for (int i = 0; i < 4; ++i) {                                          \
            async_ld16(pb[i], &sB[(ST) * 16384 + (i * 256 + wave * 64) * 16]); \
            pb[i] += 128;                                                      \
        }                                                                      \
    } while (0)

#define F8_STEP(ST) do {                                                       \
        asm volatile("" ::: "memory");                                         \
        __builtin_amdgcn_s_waitcnt(WAIT_VM(8));   /* this tile landed */       \
        __builtin_amdgcn_s_barrier();                                          \
        asm volatile("" ::: "memory");                                         \
        int8v a8[4], b8[4];                                                    \
        _Pragma("unroll")                                                      \
        for (int i = 0; i < 4; ++i) {                                          \
            int4v lo = *(const int4v*)&sA[(ST) * 16384 + oA0 + i * 2048];      \
            int4v hi = *(const int4v*)&sA[(ST) * 16384 + oA1 + i * 2048];      \
            a8[i] = __builtin_shufflevector(lo, hi, 0, 1, 2, 3, 4, 5, 6, 7);   \
        }                                                                      \
        _Pragma("unroll")                                                      \
        for (int j = 0; j < 4; ++j) {                                          \
            int4v lo = *(const int4v*)&sB[(ST) * 16384 + oB0 + j * 2048];      \
            int4v hi = *(const int4v*)&sB[(ST) * 16384 + oB1 + j * 2048];      \
            b8[j] = __builtin_shufflevector(lo, hi, 0, 1, 2, 3, 4, 5, 6, 7);   \
        }                                                                      \
        asm volatile("" ::: "memory");                                         \
        __builtin_amdgcn_s_waitcnt(WAIT_LGKM(0)); /* frags landed */           \
        __builtin_amdgcn_s_barrier();             /* stage reusable */         \
        asm volatile("" ::: "memory");                                         \
        F8_ISSUE(ST);                             /* tile kt+2 -> stage ST */  \
        _Pragma("unroll")                                                      \
        for (int i = 0; i < 4; ++i)                                            \
            _Pragma("unroll")                                                  \
            for (int j = 0; j < 4; ++j)                                        \
                acc[i][j] = __builtin_amdgcn_mfma_scale_f32_16x16x128_f8f6f4(  \
                    a8[i], b8[j], acc[i][j], 0, 0, 0, SA, 0, SB);              \
    } while (0)

    const int nit = K >> 8;        // (K/128)/2 double-steps; K mult of 256
    F8_ISSUE(0);
    F8_ISSUE(1);
    for (int it = 0; it < nit; ++it) {
        F8_STEP(0);
        F8_STEP(1);
    }
#undef F8_STEP
#undef F8_ISSUE
    asm volatile("" ::: "memory");
    __builtin_amdgcn_s_waitcnt(WAIT_VM(0));       // drain 2 garbage tail tiles

    // epilogue: C/D layout col = lane&15, row = (lane>>4)*4 + reg
    if (MODE == 0) {
#pragma unroll
        for (int i = 0; i < 4; ++i) {
            const int row = m0 + wm * 64 + i * 16 + q * 4;
#pragma unroll
            for (int j = 0; j < 4; ++j) {
                const int col = n0 + wn * 64 + j * 16 + lr;
                const float bc = bias[col];
#pragma unroll
                for (int r = 0; r < 4; ++r)
                    outb[(size_t)(row + r) * N + col] = __float2bfloat16(acc[i][j][r] + bc);
            }
        }
    } else if (MODE == 1) {
#pragma unroll
        for (int i = 0; i < 4; ++i) {
            float rs[4] = {0.f, 0.f, 0.f, 0.f};
#pragma unroll
            for (int j = 0; j < 4; ++j) {
                const int col = n0 + wn * 64 + j * 16 + lr;
                const float bc = bias[col];
#pragma unroll
                for (int r = 0; r < 4; ++r) {
                    float v = acc[i][j][r] + bc;
                    float sp = (v > 20.f) ? v : log1pf(expf(v));
                    rs[r] += sp;
                }
            }
#pragma unroll
            for (int r = 0; r < 4; ++r) {
                float v = rs[r];
                v += __shfl_xor(v, 1); v += __shfl_xor(v, 2);
                v += __shfl_xor(v, 4); v += __shfl_xor(v, 8);
                if (lr == 0)
                    atomicAdd(&rowsum[m0 + wm * 64 + i * 16 + q * 4 + r], v);
            }
        }
    } else {
        // out = resid + ys[row]*acc + bias  (y@W^T == diag(ys)*(S@W^T))
#pragma unroll
        for (int i = 0; i < 4; ++i) {
            const int row = m0 + wm * 64 + i * 16 + q * 4;
#pragma unroll
            for (int j = 0; j < 4; ++j) {
                const int col = n0 + wn * 64 + j * 16 + lr;
                const float bc = bias[col];
#pragma unroll
                for (int r = 0; r < 4; ++r) {
                    const size_t idx = (size_t)(row + r) * N + col;
                    outf[idx] = resid[idx] + ysv[row + r] * acc[i][j][r] + bc;
                }
            }
        }
    }
}

// ---------------------------------------------------------------------------
// fused elementwise pass over xp: depthwise conv(k=3)+bias+SiLU on main half
// -> xc (bf16, for bcd) + xc*16 (fp8, GEMM2 A); SiLU on gate half
// -> S*16 (fp8, GEMM3 A; ys factored out into GEMM3's epilogue).
// ---------------------------------------------------------------------------
__global__ void conv_gate_k(const __hip_bfloat16* __restrict__ xp,
                            const float* __restrict__ cw,
                            const float* __restrict__ cb,
                            __hip_bfloat16* __restrict__ xc,
                            int2* __restrict__ xc8,
                            int2* __restrict__ s8) {
    const int idx8 = blockIdx.x * blockDim.x + threadIdx.x;
    const int e = (idx8 & (Esz / 8 - 1)) * 8;
    const int r = idx8 >> 8;
    const int t = r & (Tsz - 1);
    const unsigned short* row0 = (const unsigned short*)(xp + (size_t)r * (2 * Esz) + e);
    short8 vm1 = (t > 0)       ? *(const short8*)(row0 - 2 * Esz) : (short8){0,0,0,0,0,0,0,0};
    short8 v00 = *(const short8*)row0;
    short8 vp1 = (t < Tsz - 1) ? *(const short8*)(row0 + 2 * Esz) : (short8){0,0,0,0,0,0,0,0};
    short8 o;
    float sil[8];
#pragma unroll
    for (int k = 0; k < 8; ++k) {
        const int ek = e + k;
        float v = bf2f((unsigned short)vm1[k]) * cw[ek * 3 + 0]
                + bf2f((unsigned short)v00[k]) * cw[ek * 3 + 1]
                + bf2f((unsigned short)vp1[k]) * cw[ek * 3 + 2] + cb[ek];
        sil[k] = v * sigmoidf_(v);
        __hip_bfloat16 h = __float2bfloat16(sil[k]);
        o[k] = *(short*)&h;
    }
    *(short8*)(xc + (size_t)idx8 * 8) = o;
    int2 p;
    p.x = pk_fp8x4(sil[0] * 16.f, sil[1] * 16.f, sil[2] * 16.f, sil[3] * 16.f);
    p.y = pk_fp8x4(sil[4] * 16.f, sil[5] * 16.f, sil[6] * 16.f, sil[7] * 16.f);
    xc8[idx8] = p;

    // gate half -> S = silu(gate) * 16, fp8
    short8 g = *(const short8*)(row0 + Esz);
    float sg[8];
#pragma unroll
    for (int k = 0; k < 8; ++k) {
        const float gv = bf2f((unsigned short)g[k]);
        sg[k] = gv * sigmoidf_(gv);
    }
    int2 ps;
    ps.x = pk_fp8x4(sg[0] * 16.f, sg[1] * 16.f, sg[2] * 16.f, sg[3] * 16.f);
    ps.y = pk_fp8x4(sg[4] * 16.f, sg[5] * 16.f, sg[6] * 16.f, sg[7] * 16.f);
    s8[idx8] = ps;
}

// ---------------------------------------------------------------------------
// pack B_w/C_w/D_w (each [16,2048] fp32) into Wb [48,2048] bf16
// ---------------------------------------------------------------------------
__global__ void pack_bcd(const float* __restrict__ Bw, const float* __restrict__ Cw,
                         const float* __restrict__ Dw, __hip_bfloat16* __restrict__ Wb) {
    const int idx = blockIdx.x * blockDim.x + threadIdx.x;
    if (idx >= 48 * Esz) return;
    const int row = idx >> 11, col = idx & (Esz - 1);
    float v;
    if (row < 16)      v = Bw[row * Esz + col];
    else if (row < 32) v = Cw[(row - 16) * Esz + col];
    else               v = Dw[(row - 32) * Esz + col];
    Wb[idx] = __float2bfloat16(v);
}

// ---------------------------------------------------------------------------
// B/C/D projections via MFMA skinny GEMM: xc[M,E] @ Wb[48,E]^T.
// ---------------------------------------------------------------------------
__launch_bounds__(256)
__global__ void bcd_mfma(const __hip_bfloat16* __restrict__ xc,
                         const __hip_bfloat16* __restrict__ Wb,
                         const float* __restrict__ Bb, const float* __restrict__ Cb,
                         const float* __restrict__ Db,
                         float* __restrict__ u, float* __restrict__ Ct) {
    __shared__ __align__(16) __hip_bfloat16 sA[64 * 32];
    __shared__ __align__(16) __hip_bfloat16 sW[48 * 32];
    const int tid = threadIdx.x;
    const int wave = tid >> 6, lane = tid & 63;
    const int q = lane >> 4, lr = lane & 15;
    const int m0 = blockIdx.x * 64;

    floatx4 acc[3];
#pragma unroll
    for (int j = 0; j < 3; ++j) acc[j] = (floatx4){0.f, 0.f, 0.f, 0.f};

    const int ra = wave * 16 + (lane >> 2);
    const int ca = (lane & 3) * 8;

    for (int kt = 0; kt < (Esz >> 5); ++kt) {
        const int k0 = kt << 5;
        __syncthreads();
        async_ld16(&xc[(size_t)(m0 + ra) * Esz + k0 + ca], &sA[wave * 512]);
        if (wave < 3)
            async_ld16(&Wb[(size_t)ra * Esz + k0 + ca], &sW[wave * 512]);
        __syncthreads();

        short8 af = *(const short8*)&sA[(wave * 16 + lr) * 32 + q * 8];
#pragma unroll
        for (int j = 0; j < 3; ++j) {
            short8 wf = *(const short8*)&sW[(j * 16 + lr) * 32 + q * 8];
            acc[j] = __builtin_amdgcn_mfma_f32_16x16x32_bf16(af, wf, acc[j], 0, 0, 0);
        }
    }

    const int row = m0 + wave * 16 + q * 4;
    const float bb = Bb[lr], cbv = Cb[lr], db = Db[lr];
#pragma unroll
    for (int r = 0; r < 4; ++r) {
        const float bt = acc[0][r] + bb;
        const float ct = acc[1][r] + cbv;
        const float dt = acc[2][r] + db;
        u [(size_t)(row + r) * Ssz + lr] = bt * dt;
        Ct[(size_t)(row + r) * Ssz + lr] = ct;
    }
}

// ---------------------------------------------------------------------------
// Sequential SSM scan (decay computed inline from rowsum).  One block/batch.
// ---------------------------------------------------------------------------
__global__ void scan_k(const float* __restrict__ rowsum, const float* __restrict__ u,
                       const float* __restrict__ Ct, float* __restrict__ ys) {
    const int b = blockIdx.x;
    const int tid = threadIdx.x;
    const int lane = tid & 63, wave = tid >> 6;
    __shared__ __align__(16) float su[256 * Ssz];
    __shared__ __align__(16) float sc[256 * Ssz];
    __shared__ float sp[256 * 17];
    __shared__ float sd[256];
    float st = 0.f;
    for (int t0 = 0; t0 < Tsz; t0 += 256) {
        __syncthreads();
        const float4* ub = (const float4*)(u  + ((size_t)b * Tsz + t0) * Ssz);
        const float4* cb = (const float4*)(Ct + ((size_t)b * Tsz + t0) * Ssz);
#pragma unroll
        for (int i = 0; i < 4; ++i) {
            ((float4*)su)[tid + i * 256] = ub[tid + i * 256];
            ((float4*)sc)[tid + i * 256] = cb[tid + i * 256];
        }
        {
            const float m = rowsum[b * Tsz + t0 + tid] * (1.f / (float)Esz);
            sd[tid] = expf(fminf(fmaxf(-m, -10.f), 10.f));
        }
        __syncthreads();
        if (wave == 0 && lane < 16) {
#pragma unroll 8
            for (int i = 0; i < 256; ++i) {
                st = st * sd[i] + su[i * Ssz + lane];
                sp[i * 17 + lane] = sc[i * Ssz + lane] * st;
            }
        }
        __syncthreads();
        float s = 0.f;
#pragma unroll
        for (int j = 0; j < 16; ++j) s += sp[tid * 17 + j];
        ys[b * Tsz + t0 + tid] = s;
    }
}

// ---------------------------------------------------------------------------
extern "C" void kernel_launch(void* const* d_in, const int* in_sizes, int n_in,
                              void* d_out, int out_size, void* d_ws, size_t ws_size,
                              hipStream_t stream) {
    const float* x      = (const float*)d_in[0];
    const float* in_w   = (const float*)d_in[1];
    const float* in_b   = (const float*)d_in[2];
    const float* conv_w = (const float*)d_in[3];
    const float* conv_b = (const float*)d_in[4];
    const float* dt_w   = (const float*)d_in[5];
    const float* dt_b   = (const float*)d_in[6];
    const float* B_w    = (const float*)d_in[7];
    const float* B_b    = (const float*)d_in[8];
    const float* C_w    = (const float*)d_in[9];
    const float* C_b    = (const float*)d_in[10];
    const float* D_w    = (const float*)d_in[11];
    const float* D_b    = (const float*)d_in[12];
    const float* out_w  = (const float*)d_in[13];
    const float* out_b  = (const float*)d_in[14];
    float* out = (float*)d_out;

    char* ws = (char*)d_ws;
    auto alloc = [&](size_t bytes) {
        char* p = ws;
        ws += (bytes + 255) & ~(size_t)255;
        return p;
    };
    unsigned char* x_f8    = (unsigned char*)alloc((size_t)Mrows * Dsz);          //  8 MB
    unsigned char* inw_f8  = (unsigned char*)alloc((size_t)2 * Esz * Dsz);        //  4 MB
    unsigned char* dtw_f8  = (unsigned char*)alloc((size_t)Esz * Esz);            //  4 MB
    unsigned char* outw_f8 = (unsigned char*)alloc((size_t)Dsz * Esz);            //  2 MB
    __hip_bfloat16* xp_bf  = (__hip_bfloat16*)alloc((size_t)Mrows * 2 * Esz * 2); // 64 MB
    __hip_bfloat16* xc_bf  = (__hip_bfloat16*)alloc((size_t)Mrows * Esz * 2);     // 32 MB
    unsigned char* xc_f8   = (unsigned char*)alloc((size_t)Mrows * Esz);          // 16 MB
    unsigned char* s_f8    = (unsigned char*)alloc((size_t)Mrows * Esz);          // 16 MB
    __hip_bfloat16* wb_bf  = (__hip_bfloat16*)alloc((size_t)48 * Esz * 2);
    float* rowsum = (float*)alloc(Mrows * 4);
    float* u_buf  = (float*)alloc((size_t)Mrows * Ssz * 4);
    float* ct_buf = (float*)alloc((size_t)Mrows * Ssz * 4);
    float* ys_buf = (float*)alloc(Mrows * 4);
    (void)alloc(65536);            // pad: fp8 tail over-reads stay inside ws

    hipMemsetAsync(rowsum, 0, Mrows * 4, stream);

    // conversions: x/in_w/dt_w/out_w -> fp8 (weights x64)
    cvt_all<<<4608, 256, 0, stream>>>((const float4*)x, (const float4*)in_w,
                                      (const float4*)dt_w, (const float4*)out_w,
                                      (int*)x_f8, (int*)inw_f8, (int*)dtw_f8,
                                      (int*)outw_f8);
    pack_bcd<<<48 * Esz / 256, 256, 0, stream>>>(B_w, C_w, D_w, wb_bf);

    // GEMM1 (MX-fp8 128x128): xp = x @ in_w^T + in_b  (8192x4096x1024) -> bf16
    // scales: A = x (2^0 -> 127), B = in_w*64 (2^-6 -> 121)
    gemm_f8<0, 127, 121><<<dim3(4096 / 128, Mrows / 128), 256, 0, stream>>>(
        x_f8, inw_f8, in_b, Mrows, 4096, 1024, xp_bf, nullptr, nullptr, nullptr, nullptr);

    // fused conv+SiLU (-> xc bf16, xc*16 fp8) + gate SiLU (-> S*16 fp8)
    conv_gate_k<<<(Mrows * Esz / 8) / 256, 256, 0, stream>>>(
        xp_bf, conv_w, conv_b, xc_bf, (int2*)xc_f8, (int2*)s_f8);

    // GEMM2 (MX-fp8): softplus(xc @ dt_w^T + dt_b) row-sums (8192x2048x2048)
    // scales: A = xc*16 (2^-4 -> 123), B = dt_w*64 (2^-6 -> 121)
    gemm_f8<1, 123, 121><<<dim3(Esz / 128, Mrows / 128), 256, 0, stream>>>(
        xc_f8, dtw_f8, dt_b, Mrows, Esz, Esz, nullptr, rowsum, nullptr, nullptr, nullptr);

    // B/C/D projections + u = Bt*Dt (bf16 xc)
    bcd_mfma<<<Mrows / 64, 256, 0, stream>>>(xc_bf, wb_bf, B_b, C_b, D_b, u_buf, ct_buf);

    // sequential scan (decay inline) -> ys
    scan_k<<<Bsz, 256, 0, stream>>>(rowsum, u_buf, ct_buf, ys_buf);

    // GEMM3 (MX-fp8): out = x + ys[row]*(S @ out_w^T) + out_b (8192x1024x2048)
    // scales: A = S*16 (2^-4 -> 123), B = out_w*64 (2^-6 -> 121)
    gemm_f8<2, 123, 121><<<dim3(Dsz / 128, Mrows / 128), 256, 0, stream>>>(
        s_f8, outw_f8, out_b, Mrows, Dsz, Esz, nullptr, nullptr, x, ys_buf, out);
}